// Round 6
// baseline (117.819 us; speedup 1.0000x reference)
//
#include <hip/hip_runtime.h>
#include <hip/hip_bf16.h>

#define FDIM 256
#define K2   512
#define DNB  32
#define TM   32
#define NMAX 100000
#define TMAX 20480
#define CONVB 1024

typedef __attribute__((ext_vector_type(8))) short bf16x8;
typedef __attribute__((ext_vector_type(4))) float f32x4;

// Device-global scratch & precomputed weights (fully rewritten every launch).
__device__ __align__(16) unsigned short g_FD[(size_t)NMAX * FDIM]; // bf16 feat_data
__device__ float g_deg[NMAX];                                      // feats[n][0]
__device__ __align__(16) unsigned short g_X[(size_t)TMAX * K2];    // bf16 gathered rows
__device__ float g_Sdeg[TMAX];
__device__ __align__(16) unsigned short g_Wc[FDIM * K2];           // [o][k] bf16
__device__ float g_c2[FDIM];
__device__ float g_c3[FDIM];

__device__ __forceinline__ unsigned short f2bf(float f) {
    __hip_bfloat16 h = __float2bfloat16(f);
    return *reinterpret_cast<unsigned short*>(&h);
}
__device__ __forceinline__ float bf2f(unsigned short u) {
    return __uint_as_float(((unsigned)u) << 16);
}
__device__ __forceinline__ ushort4 cvt4(float4 v) {
    return make_ushort4(f2bf(v.x), f2bf(v.y), f2bf(v.z), f2bf(v.w));
}

// ---------- 1) prep ----------
// blocks [0,256): weight combine (16-wide batched loads) + degree table
// blocks [256,256+CONVB): feat_data -> bf16, grid-stride copy, 4-deep batches
__global__ __launch_bounds__(512) void prep(const float* __restrict__ fd,
                                            const float* __restrict__ feats,
                                            const float* __restrict__ W1,
                                            const float* __restrict__ W2,
                                            const float* __restrict__ b1,
                                            const float* __restrict__ b2,
                                            float Dmul, int N) {
    __shared__ float w2s[FDIM];
    __shared__ float rv[8], ru[8];
    int bid = blockIdx.x;
    int tid = threadIdx.x;

    if (bid >= 256) {
        // ---- conversion: flat grid-stride copy fp32 -> bf16
        size_t total4 = (size_t)N * (FDIM / 4);            // # float4 groups
        size_t stride = (size_t)CONVB * 512;
        size_t i = (size_t)(bid - 256) * 512 + tid;
        const float4* in4 = (const float4*)fd;
        ushort4* out4 = (ushort4*)g_FD;

        while (i + 3 * stride < total4) {
            float4 a0 = in4[i];
            float4 a1 = in4[i + stride];
            float4 a2 = in4[i + 2 * stride];
            float4 a3 = in4[i + 3 * stride];
            out4[i]              = cvt4(a0);
            out4[i + stride]     = cvt4(a1);
            out4[i + 2 * stride] = cvt4(a2);
            out4[i + 3 * stride] = cvt4(a3);
            i += 4 * stride;
        }
        for (; i < total4; i += stride)
            out4[i] = cvt4(in4[i]);
        return;
    }

    // ---- weight combine: o = bid, k' = tid in [0,512)
    int o = bid, k = tid;

    // degree table rides here: 256 blocks x 512 threads = 131072 >= N
    int n = o * 512 + k;
    if (n < N) g_deg[n] = feats[(size_t)n * FDIM];

    if (k < FDIM) w2s[k] = W2[(size_t)o * K2 + FDIM + k];
    __syncthreads();

    const float* w1col = W1 + k;
    float acc = 0.f;
    for (int j = 0; j < FDIM; j += 16) {
        float r[16];
        #pragma unroll
        for (int u = 0; u < 16; ++u) r[u] = w1col[(size_t)(j + u) * K2];
        #pragma unroll
        for (int u = 0; u < 16; ++u) acc = fmaf(w2s[j + u], r[u], acc);
    }

    if (k < FDIM) {
        g_Wc[(size_t)o * K2 + FDIM + k] = f2bf(acc);                    // C1 half
        g_Wc[(size_t)o * K2 + k]        = f2bf(W2[(size_t)o * K2 + k]); // W2a half
    }
    float v = (k >= FDIM) ? acc : 0.f;            // -> c2
    float u = (k < FDIM) ? b1[k] * w2s[k] : 0.f;  // -> c3 dot
    #pragma unroll
    for (int s = 32; s; s >>= 1) { v += __shfl_down(v, s); u += __shfl_down(u, s); }
    if ((k & 63) == 0) { rv[k >> 6] = v; ru[k >> 6] = u; }
    __syncthreads();
    if (k == 0) {
        float sv = 0.f, su = 0.f;
        #pragma unroll
        for (int w = 0; w < 8; ++w) { sv += rv[w]; su += ru[w]; }
        g_c2[o] = sv;
        g_c3[o] = b2[o] + Dmul * su;
    }
}

// ---------- 2) gather: one wave per node; 2 neighbors in parallel (16B/lane) ----------
__global__ __launch_bounds__(256, 6) void gather(
    const int* __restrict__ adj,
    const int* __restrict__ in1, int B1,
    const int* __restrict__ in2, int B2,
    const int* __restrict__ neg, int total)
{
    int wave = threadIdx.x >> 6, lane = threadIdx.x & 63;
    int half = lane >> 5, l31 = lane & 31;
    int t = blockIdx.x * 4 + wave;
    if (t >= total) return;
    int node = (t < B1) ? in1[t] : ((t < B1 + B2) ? in2[t - B1] : neg[t - B1 - B2]);

    int idx = 0; float deg = 0.f;
    if (lane < DNB) {
        idx = adj[(size_t)node * DNB + lane];
        deg = g_deg[idx];
    }
    #pragma unroll
    for (int s = 16; s; s >>= 1) deg += __shfl_down(deg, s);
    if (lane == 0) g_Sdeg[t] = deg;

    // node row passthrough (already bf16): 8B/lane
    ushort4 nf = *(const ushort4*)(g_FD + (size_t)node * FDIM + lane * 4);
    *(ushort4*)(g_X + (size_t)t * K2 + lane * 4) = nf;

    // neighbor sum: half-wave h covers neighbors d+2u+h; lane covers cols l31*8..+7
    float acc[8];
    #pragma unroll
    for (int k = 0; k < 8; ++k) acc[k] = 0.f;
    #pragma unroll
    for (int d = 0; d < DNB; d += 8) {
        bf16x8 v[4];
        #pragma unroll
        for (int u = 0; u < 4; ++u) {
            int nb = __shfl(idx, d + u * 2 + half);
            v[u] = *(const bf16x8*)(g_FD + (size_t)nb * FDIM + l31 * 8);
        }
        #pragma unroll
        for (int u = 0; u < 4; ++u)
            #pragma unroll
            for (int k = 0; k < 8; ++k)
                acc[k] += bf2f((unsigned short)v[u][k]);
    }
    // combine even/odd-neighbor halves
    #pragma unroll
    for (int k = 0; k < 8; ++k) acc[k] += __shfl_xor(acc[k], 32);

    if (lane < 32) {
        bf16x8 ah;
        #pragma unroll
        for (int k = 0; k < 8; ++k) ah[k] = (short)f2bf(acc[k]);
        *(bf16x8*)(g_X + (size_t)t * K2 + FDIM + l31 * 8) = ah;
    }
}

// ---------- 3) GEMM (MFMA) + degree term + L2 normalize ----------
__global__ __launch_bounds__(256, 4) void gemm_norm(float* __restrict__ out, int total)
{
    __shared__ __align__(16) char lds[TM * 1024];  // bf16 [32][512]; reused f32 [32][256]
    __shared__ float Sdeg[TM];

    int tid = threadIdx.x, wave = tid >> 6, lane = tid & 63;
    int base = blockIdx.x * TM;

    if (tid < TM) {
        int t = base + tid;
        Sdeg[tid] = (t < total) ? g_Sdeg[t] : 0.f;
    }
    // stage X rows (coalesced 16B/lane), swizzled LDS writes
    #pragma unroll
    for (int i = 0; i < 8; ++i) {
        int row = wave * 8 + i;
        int t = base + row;
        bf16x8 v = {0, 0, 0, 0, 0, 0, 0, 0};
        if (t < total) v = *(const bf16x8*)(g_X + (size_t)t * K2 + lane * 8);
        *(bf16x8*)(lds + row * 1024 + ((lane * 16) ^ ((row & 7) << 4))) = v;
    }
    __syncthreads();

    // MFMA: wave w -> cols w*64 (4 tiles of 16), rows 0..31 (2 tiles)
    int l15 = lane & 15, lg = lane >> 4;
    int swzA = (l15 & 7) << 4;
    f32x4 acc[2][4];
    #pragma unroll
    for (int mt = 0; mt < 2; ++mt)
        #pragma unroll
        for (int nt = 0; nt < 4; ++nt) acc[mt][nt] = (f32x4){0.f, 0.f, 0.f, 0.f};

    const char* pA0 = lds + (size_t)l15 * 1024;
    const char* pA1 = lds + (size_t)(16 + l15) * 1024;
    const unsigned short* wcB = g_Wc + (size_t)(wave * 64 + l15) * K2 + lg * 8;

    #pragma unroll 4
    for (int kk = 0; kk < K2; kk += 32) {
        int kb = kk * 2 + lg * 16;
        bf16x8 a0 = *(const bf16x8*)(pA0 + (kb ^ swzA));
        bf16x8 a1 = *(const bf16x8*)(pA1 + (kb ^ swzA));
        #pragma unroll
        for (int nt = 0; nt < 4; ++nt) {
            bf16x8 b = *(const bf16x8*)(wcB + (size_t)nt * 16 * K2 + kk);
            acc[0][nt] = __builtin_amdgcn_mfma_f32_16x16x32_bf16(a0, b, acc[0][nt], 0, 0, 0);
            acc[1][nt] = __builtin_amdgcn_mfma_f32_16x16x32_bf16(a1, b, acc[1][nt], 0, 0, 0);
        }
    }
    __syncthreads();

    // stage raw acc to LDS as f32 [32][256] (HW-verified D layout)
    float* outf = (float*)lds;
    #pragma unroll
    for (int mt = 0; mt < 2; ++mt)
        #pragma unroll
        for (int nt = 0; nt < 4; ++nt)
            #pragma unroll
            for (int r = 0; r < 4; ++r) {
                int row = mt * 16 + lg * 4 + r;
                int col = wave * 64 + nt * 16 + l15;
                outf[row * 256 + col] = acc[mt][nt][r];
            }
    __syncthreads();

    // epilogue: v = acc + Sdeg*c2 + c3 (fp32), L2-normalize, store
    float4 c2v = *(const float4*)(g_c2 + lane * 4);
    float4 c3v = *(const float4*)(g_c3 + lane * 4);
    for (int r = 0; r < 8; ++r) {
        int row = wave * 8 + r;
        int t = base + row;
        if (t >= total) break;                   // wave-uniform
        float sd = Sdeg[row];
        float4 v = *(float4*)(outf + row * 256 + lane * 4);
        v.x += sd * c2v.x + c3v.x;
        v.y += sd * c2v.y + c3v.y;
        v.z += sd * c2v.z + c3v.z;
        v.w += sd * c2v.w + c3v.w;
        float ss = v.x * v.x + v.y * v.y + v.z * v.z + v.w * v.w;
        #pragma unroll
        for (int s = 32; s; s >>= 1) ss += __shfl_xor(ss, s);
        float inv = 1.0f / fmaxf(sqrtf(ss), 1e-12f);
        v.x *= inv; v.y *= inv; v.z *= inv; v.w *= inv;
        *(float4*)(out + (size_t)t * FDIM + lane * 4) = v;
    }
}

extern "C" void kernel_launch(void* const* d_in, const int* in_sizes, int n_in,
                              void* d_out, int out_size, void* d_ws, size_t ws_size,
                              hipStream_t stream) {
    const float* feat_data = (const float*)d_in[0];
    const float* feats     = (const float*)d_in[1];
    const float* W1        = (const float*)d_in[2];
    const float* b1        = (const float*)d_in[3];
    const float* W2        = (const float*)d_in[4];
    const float* b2        = (const float*)d_in[5];
    const int*   adj       = (const int*)d_in[6];
    const int*   in1       = (const int*)d_in[7];
    const int*   in2       = (const int*)d_in[8];
    const int*   neg       = (const int*)d_in[9];

    int B1 = in_sizes[7];
    int B2 = in_sizes[8];
    int Bn = in_sizes[9];
    int N  = in_sizes[0] / FDIM;
    int D  = in_sizes[6] / N;   // == 32

    float* out = (float*)d_out;
    int total = B1 + B2 + Bn;

    prep<<<256 + CONVB, 512, 0, stream>>>(feat_data, feats, W1, W2, b1, b2,
                                          (float)D, N);
    gather<<<(total + 3) / 4, 256, 0, stream>>>(adj, in1, B1, in2, B2, neg, total);
    gemm_norm<<<(total + TM - 1) / TM, 256, 0, stream>>>(out, total);
}